// Round 17
// baseline (79.303 us; speedup 1.0000x reference)
//
#include <hip/hip_runtime.h>
#include <hip/hip_bf16.h>

#define N_  32
#define ND_ 16
#define ED_ 8
#define GD_ 8
#define HN_ 128
#define HE_ 128
#define HG_ 128
#define HC_ 64

typedef __attribute__((ext_vector_type(8))) short short8_t;
typedef __attribute__((ext_vector_type(4))) float f32x4;

#define MFMA16(a, b, c) __builtin_amdgcn_mfma_f32_16x16x32_bf16((a), (b), (c), 0, 0, 0)

__device__ __forceinline__ unsigned short f2bf(float f) {
    unsigned int u = __float_as_uint(f);
    unsigned int r = u + 0x7FFFu + ((u >> 16) & 1u);
    return (unsigned short)(r >> 16);
}
__device__ __forceinline__ float bf2f(unsigned short h) {
    return __uint_as_float(((unsigned int)h) << 16);
}

// ---- workspace layout (ushort elements) ----
#define WNS_HI 0
#define WNS_LO 4096
#define WES_HI 8192
#define WES_LO (8192 + 36864)
#define WS_USHORTS (8192 + 2 * 36864)
#define WS_BYTES (WS_USHORTS * 2)

// Prologue: convert + swizzle weights into B-fragment-major bf16 hi/lo.
// lane l holds B[k = 32*s + 8*(l>>4)+i][col = 16*n + (l&15)]
// Edge sets 0..4 = W1' (We rows 8..135 then 0..7 then zero-pad to K=160);
// sets 5..8 = W2 (We rows 136..263).
__global__ void prep_weights(const float* __restrict__ Wn,
                             const float* __restrict__ We,
                             unsigned short* __restrict__ wsp) {
    int gid = blockIdx.x * 256 + threadIdx.x;
    if (gid >= 512 + 4608) return;
    float vals[8];
    unsigned short* dh;
    unsigned short* dl;
    if (gid < 512) {
        int l = gid & 63, n = (gid >> 6) & 7;
        int c = 16 * n + (l & 15);
#pragma unroll
        for (int i = 0; i < 8; ++i) {
            int k = 8 * (l >> 4) + i;
            vals[i] = Wn[k * HN_ + c];
        }
        dh = wsp + WNS_HI + gid * 8;
        dl = wsp + WNS_LO + gid * 8;
    } else {
        int g2 = gid - 512;
        int l = g2 & 63, n = (g2 >> 6) & 7, s = g2 >> 9;   // s in 0..8
        int c = 16 * n + (l & 15);
#pragma unroll
        for (int i = 0; i < 8; ++i) {
            int kl = 8 * (l >> 4) + i;
            int ks;
            if (s <= 4) {                      // W1': hn(128) | ef(8) | 0(24)
                int kf = s * 32 + kl;          // 0..159
                ks = (kf < 128) ? (8 + kf) : ((kf < 136) ? (kf - 128) : -1);
            } else {                           // W2: h_node[e+1]
                ks = 136 + (s - 5) * 32 + kl;
            }
            vals[i] = (ks >= 0) ? We[ks * HE_ + c] : 0.0f;
        }
        dh = wsp + WES_HI + g2 * 8;
        dl = wsp + WES_LO + g2 * 8;
    }
    unsigned short h[8], lo[8];
#pragma unroll
    for (int i = 0; i < 8; ++i) {
        h[i] = f2bf(vals[i]);
        lo[i] = f2bf(vals[i] - bf2f(h[i]));
    }
    *(short8_t*)dh = *(short8_t*)h;
    *(short8_t*)dl = *(short8_t*)lo;
}

#define HNS 168   // hn' row stride (ushorts): 336B = 84 dwords (== 20 mod 32, benign)
#define NIS 40    // nin row stride (ushorts): 80B = 20 dwords (== 20 mod 32, benign)
#define HES 128   // he f32 row stride (with XOR col swizzle below)
// XOR swizzle: physical col = logical col ^ ((row&7)<<2). Involution; flips
// bits 2..4 only, so any 4-aligned float4 group maps to a 4-aligned group.
#define HESWZ(row, col) ((col) ^ (((row) & 7) << 2))

// Load 4 edge B-fragments of set ss (0..4 = W1' steps, 5..8 = W2 steps).
// [0],[1] = hi (n-tiles 2w, 2w+1); [2],[3] = lo.
#define LOADB(Bv, ss) do {                                                      \
    Bv[0] = *(const short8_t*)(wsp + WES_HI + ((ss)*8 + 2*w)     * 512 + l*8);  \
    Bv[1] = *(const short8_t*)(wsp + WES_HI + ((ss)*8 + 2*w + 1) * 512 + l*8);  \
    Bv[2] = *(const short8_t*)(wsp + WES_LO + ((ss)*8 + 2*w)     * 512 + l*8);  \
    Bv[3] = *(const short8_t*)(wsp + WES_LO + ((ss)*8 + 2*w + 1) * 512 + l*8);  \
} while (0)

// 2 graphs / 256-thread block, ~40KB LDS -> 4 blocks/CU.
// Weights fetched once per PAIR. hn + nin single bf16. Bank-conflict-free LDS.
__global__ __launch_bounds__(256, 4) void gnn_mfma11(
    const float* __restrict__ gf, const float* __restrict__ nf,
    const float* __restrict__ ef, const void* __restrict__ nmask_raw,
    const float* __restrict__ Wn, const float* __restrict__ bn,
    const float* __restrict__ We, const float* __restrict__ be,
    const float* __restrict__ Ws, const float* __restrict__ bs,
    const float* __restrict__ Wg, const float* __restrict__ bg,
    const float* __restrict__ Wc1, const float* __restrict__ bc1,
    const float* __restrict__ Wc2, const float* __restrict__ bc2,
    const unsigned short* __restrict__ wsp,
    float* __restrict__ out, int Btot)
{
    const int b = blockIdx.x;
    const int t = threadIdx.x;
    const int gid0 = 2 * b;
    const int gid1 = (2 * b + 1 < Btot) ? (2 * b + 1) : (Btot - 1);

    // UNI: { hn(g0)[33][168] @0 | hn(g1) @11088 | nin[64][40] @22176 (27296B) }
    //      -> overlaid by he f32 [64][128] (32768B) after edge barrier
    __shared__ __align__(16) unsigned char UNI[32768];
    // U3: { efrF f32[64][8] @0 (A->C) -> tmpF[512] @0 | aggf[2][128] @2048 | hg[2][128] @3072 }
    __shared__ __align__(16) unsigned char U3[4096];
    __shared__ __align__(16) float s_bias1[2][HN_];
    __shared__ __align__(16) float s_bias2[2][HE_];
    __shared__ float s_g[2][GD_];
    __shared__ int   s_mi[2][N_];
    __shared__ float s_emask[2][N_];
    __shared__ float s_sc[2][N_];
    __shared__ float s_w[2][N_];

#define HNG(g, row) ((unsigned short*)(UNI + (g) * 11088) + (row) * HNS)
    unsigned short* ninH = (unsigned short*)(UNI + 22176);   // [64][40]
#define NINR(r) (ninH + (r) * NIS)
    float* heF  = (float*)UNI;                               // [64][128] (swizzled cols)
    float* efrF = (float*)U3;                                // [64][8]
    float* tmpF = (float*)U3;                                // [512] (P5+)
    float* aggf = (float*)(U3 + 2048);                       // [2][128]
    float* hgF  = (float*)(U3 + 3072);                       // [2][128]

    // ---- mask dtype detection (u8 vs i32), deterministic ----
    const unsigned char* mb = (const unsigned char*)nmask_raw;
    int cnt = __syncthreads_count(mb[t] != 0);
    const bool is_u8 = (cnt > 96);

    // ---- Phase A: loads + zero fills ----
    if (t < 16) s_g[t >> 3][t & 7] = gf[(t >> 3 ? gid1 : gid0) * GD_ + (t & 7)];
#pragma unroll
    for (int ii = 0; ii < 4; ++ii) {                 // node feats 2x32x16 -> single bf16
        int idx = t + ii * 256;
        int gg = idx >> 9, rem = idx & 511;
        float v = nf[(gg ? gid1 : gid0) * 512 + rem];
        NINR(gg * 32 + (rem >> 4))[rem & 15] = f2bf(v);
    }
#pragma unroll
    for (int ii = 0; ii < 2; ++ii) {                 // raw edges f32 (row31=0)
        int idx = t + ii * 256;
        int gg = idx >> 8, rem = idx & 255, e = rem >> 3, k = rem & 7;
        efrF[(gg * 32 + e) * 8 + k] =
            (e < 31) ? ef[(gg ? gid1 : gid0) * 248 + e * 8 + k] : 0.0f;
    }
    if (t < 16) {                                     // node0 backward zero (both graphs)
        int gg = t >> 3, k = t & 7;
        NINR(gg * 32)[16 + k] = 0;
    }
    for (int idx = t; idx < 2 * HNS; idx += 256) {    // hn pad row 32 = 0 (both)
        int g = idx >= HNS, c = idx - g * HNS;
        HNG(g, N_)[c] = 0;
    }
    for (int idx = t; idx < 2 * 32 * 24; idx += 256) {  // hn cols 136..159 = 0 (both)
        int g = idx >= 768, r2 = idx - g * 768;
        int rr = r2 / 24, cc = 136 + (r2 % 24);
        HNG(g, rr)[cc] = 0;
    }
    if (t < 64) {
        int g = t >> 5, n = t & 31;
        int mv = is_u8 ? (int)mb[(g ? gid1 : gid0) * N_ + n]
                       : ((const int*)nmask_raw)[(g ? gid1 : gid0) * N_ + n];
        s_mi[g][n] = mv;
    }
    __syncthreads();

    // ---- Phase B: edge mask + combined biases (dual-graph per weight load) ----
    if (t < 64) {
        int g = t >> 5, n = t & 31;
        s_emask[g][n] = (n < 31 && s_mi[g][n] != 0 && s_mi[g][n + 1] != 0) ? 1.0f : 0.0f;
    }
    {
        int mat = t >> 7, j = t & 127;
        const float* Wt = mat ? (We + (ED_ + 2 * HN_) * HE_) : (Wn + (ND_ + 2 * ED_) * HN_);
        float base = mat ? be[j] : bn[j];
        float a0 = base, a1 = base;
#pragma unroll
        for (int k = 0; k < GD_; ++k) {
            float wv = Wt[k * 128 + j];
            a0 += s_g[0][k] * wv;
            a1 += s_g[1][k] * wv;
        }
        if (mat) { s_bias2[0][j] = a0; s_bias2[1][j] = a1; }
        else     { s_bias1[0][j] = a0; s_bias1[1][j] = a1; }
    }
    __syncthreads();

    // ---- Phase C: raw-ef -> hn cols 128..135 (single bf16); masked -> nin tail ----
#pragma unroll
    for (int ii = 0; ii < 2; ++ii) {
        int idx = t + ii * 256;
        int gg = idx >> 8, rem = idx & 255, e = rem >> 3, k = rem & 7;
        int r = gg * 32 + e;
        float vr = efrF[r * 8 + k];                       // raw (row31 = 0)
        HNG(gg, e)[128 + k] = f2bf(vr);
        bool m = (e < 31) && s_mi[gg][e] != 0 && s_mi[gg][e + 1] != 0;
        unsigned short hm = f2bf(m ? vr : 0.0f);
        if (e < 31) NINR(r + 1)[16 + k] = hm;
        NINR(r)[24 + k] = hm;
    }
    __syncthreads();

    const int w = t >> 6, l = t & 63;
    const int lrow = l & 15;
    const int lk8 = (l >> 4) * 8;
    const int g4 = (l >> 4) * 4;
    const int c0 = 32 * w + lrow, c1 = c0 + 16;

    // ---- Node MLP (MFMA, K=32, single-bf16 A, split B): 4 M-tiles (2/graph) ----
    {
        const unsigned short* pn = wsp + (2 * w) * 512 + l * 8;
        short8_t nBh0 = *(const short8_t*)(pn + WNS_HI);
        short8_t nBl0 = *(const short8_t*)(pn + WNS_LO);
        short8_t nBh1 = *(const short8_t*)(pn + WNS_HI + 512);
        short8_t nBl1 = *(const short8_t*)(pn + WNS_LO + 512);

        f32x4 acc[4][2];
#pragma unroll
        for (int mt = 0; mt < 4; ++mt) {
            int g = mt >> 1;
            float b0 = s_bias1[g][c0], b1 = s_bias1[g][c1];
            acc[mt][0] = (f32x4){b0, b0, b0, b0};
            acc[mt][1] = (f32x4){b1, b1, b1, b1};
        }
#pragma unroll
        for (int mt = 0; mt < 4; ++mt) {
            int r = (mt >> 1) * 32 + (mt & 1) * 16 + lrow;
            short8_t A = *(const short8_t*)&NINR(r)[lk8];
            acc[mt][0] = MFMA16(A, nBl0, acc[mt][0]);
            acc[mt][0] = MFMA16(A, nBh0, acc[mt][0]);
            acc[mt][1] = MFMA16(A, nBl1, acc[mt][1]);
            acc[mt][1] = MFMA16(A, nBh1, acc[mt][1]);
        }
#pragma unroll
        for (int mt = 0; mt < 4; ++mt) {
            int g = mt >> 1, rb = (mt & 1) * 16 + g4;
#pragma unroll
            for (int nt = 0; nt < 2; ++nt) {
                int col = nt ? c1 : c0;
#pragma unroll
                for (int r = 0; r < 4; ++r)
                    HNG(g, rb + r)[col] = f2bf(fmaxf(acc[mt][nt][r], 0.0f));
            }
        }
    }
    __syncthreads();

    // ---- Edge MLP (all-MFMA): acc = bias2 + hn'[e]@W1' + hn[e+1]@W2 ----
    {
        f32x4 acc[4][2];
#pragma unroll
        for (int mt = 0; mt < 4; ++mt) {
            int g = mt >> 1;
            float b0 = s_bias2[g][c0], b1 = s_bias2[g][c1];
            acc[mt][0] = (f32x4){b0, b0, b0, b0};
            acc[mt][1] = (f32x4){b1, b1, b1, b1};
        }
        short8_t B1[4], B2[4];
        LOADB(B1, 0);
#pragma unroll
        for (int s = 0; s < 4; ++s) {
            LOADB(B2, 5 + s);
            int kb = s * 32 + lk8;
#pragma unroll
            for (int mt = 0; mt < 4; ++mt) {
                int g = mt >> 1, lr = (mt & 1) * 16 + lrow;
                short8_t A1 = *(const short8_t*)&HNG(g, lr)[kb];
                acc[mt][0] = MFMA16(A1, B1[2], acc[mt][0]);
                acc[mt][0] = MFMA16(A1, B1[0], acc[mt][0]);
                acc[mt][1] = MFMA16(A1, B1[3], acc[mt][1]);
                acc[mt][1] = MFMA16(A1, B1[1], acc[mt][1]);
            }
            LOADB(B1, s + 1);    // W1' sets 1..4
#pragma unroll
            for (int mt = 0; mt < 4; ++mt) {
                int g = mt >> 1, lr = (mt & 1) * 16 + lrow;
                short8_t A2 = *(const short8_t*)&HNG(g, lr + 1)[kb];
                acc[mt][0] = MFMA16(A2, B2[2], acc[mt][0]);
                acc[mt][0] = MFMA16(A2, B2[0], acc[mt][0]);
                acc[mt][1] = MFMA16(A2, B2[3], acc[mt][1]);
                acc[mt][1] = MFMA16(A2, B2[1], acc[mt][1]);
            }
        }
        {   // final W1' step 4: ef columns (kb = 128..159)
            int kb = 128 + lk8;
#pragma unroll
            for (int mt = 0; mt < 4; ++mt) {
                int g = mt >> 1, lr = (mt & 1) * 16 + lrow;
                short8_t A1 = *(const short8_t*)&HNG(g, lr)[kb];
                acc[mt][0] = MFMA16(A1, B1[2], acc[mt][0]);
                acc[mt][0] = MFMA16(A1, B1[0], acc[mt][0]);
                acc[mt][1] = MFMA16(A1, B1[3], acc[mt][1]);
                acc[mt][1] = MFMA16(A1, B1[1], acc[mt][1]);
            }
        }
        __syncthreads();   // all hn/nin reads done -> safe to overlay he onto UNI
#pragma unroll
        for (int mt = 0; mt < 4; ++mt) {
            int g = mt >> 1, rb = (mt & 1) * 16 + g4;
#pragma unroll
            for (int nt = 0; nt < 2; ++nt) {
                int col = nt ? c1 : c0;
#pragma unroll
                for (int r = 0; r < 4; ++r) {
                    int row = g * 32 + rb + r;
                    heF[row * HES + HESWZ(row, col)] = fmaxf(acc[mt][nt][r], 0.0f);
                }
            }
        }
    }
    __syncthreads();

    // ---- P3: scores. Physical float4 at HESWZ(row, L) holds LOGICAL cols
    //      L..L+3 (XOR flips bits 2..4 only), so pair with Ws[L]. ----
    {
        int c = t & 3, eg = t >> 2;
        int g = eg >> 5, e = eg & 31;
        int row = g * 32 + e;
        const float* he = &heF[row * HES];
        float pq = 0.0f;
#pragma unroll
        for (int j0 = 0; j0 < 32; j0 += 4) {
            int L = c * 32 + j0;
            float4 h = *(const float4*)&he[HESWZ(row, L)];
            float4 wv = *(const float4*)&Ws[L];
            pq += h.x * wv.x + h.y * wv.y + h.z * wv.z + h.w * wv.w;
        }
        pq += __shfl_xor(pq, 1);
        pq += __shfl_xor(pq, 2);
        if (c == 0) s_sc[g][e] = pq + bs[0];
    }
    __syncthreads();

    // ---- masked softmax (graph g on wave g) ----
    if (t < 128) {
        int g = t >> 6, tt = t & 63;
        float v = -INFINITY;
        if (tt < 31)
            v = s_sc[g][tt] * s_emask[g][tt] + (1.0f - s_emask[g][tt]) * (-1e9f);
        float m = v;
#pragma unroll
        for (int d = 32; d >= 1; d >>= 1) m = fmaxf(m, __shfl_xor(m, d));
        float e_ = (tt < 31) ? expf(v - m) : 0.0f;
        float ssum = e_;
#pragma unroll
        for (int d = 32; d >= 1; d >>= 1) ssum += __shfl_xor(ssum, d);
        if (tt < 32) s_w[g][tt] = (tt < 31) ? (e_ / ssum) : 0.0f;
    }
    __syncthreads();

    // ---- P4: weighted edge pooling (swizzle-aware scalar reads) ----
    {
        int g = t >> 7, j = t & 127;
        float pp = 0.0f;
#pragma unroll
        for (int e = 0; e < 31; ++e) {
            int row = g * 32 + e;
            pp += heF[row * HES + HESWZ(row, j)] * s_w[g][e];
        }
        aggf[g * 128 + j] = pp;
    }
    __syncthreads();

    // ---- P5: h_glob (Wg loaded once per pair; tmpF overlays dead efrF) ----
    {
        int j = t & 127, half = t >> 7;
        float a0 = 0.0f, a1 = 0.0f;
        for (int k = half * 64; k < half * 64 + 64; ++k) {
            float wv = Wg[k * HG_ + j];
            a0 += aggf[k] * wv;
            a1 += aggf[128 + k] * wv;
        }
        tmpF[half * 256 + j] = a0;
        tmpF[half * 256 + 128 + j] = a1;
    }
    __syncthreads();
    {
        int g = t >> 7, j = t & 127;
        hgF[g * 128 + j] = fmaxf(tmpF[g * 128 + j] + tmpF[256 + g * 128 + j] + bg[j], 0.0f);
    }
    __syncthreads();

    // ---- P6: h_cls (Wc1 loaded once per pair), P7 fused ----
    {
        int j = t & 63, q = t >> 6;
        float a0 = 0.0f, a1 = 0.0f;
        for (int k = q * 32; k < q * 32 + 32; ++k) {
            float wv = Wc1[k * HC_ + j];
            a0 += hgF[k] * wv;
            a1 += hgF[128 + k] * wv;
        }
        tmpF[q * 128 + j] = a0;
        tmpF[q * 128 + 64 + j] = a1;
    }
    __syncthreads();
    if (t < 128) {
        int g = t >> 6, tt = t & 63;
        float hc = bc1[tt];
#pragma unroll
        for (int q = 0; q < 4; ++q) hc += tmpF[q * 128 + g * 64 + tt];
        hc = fmaxf(hc, 0.0f);
        float pp = hc * Wc2[tt];
#pragma unroll
        for (int d = 32; d >= 1; d >>= 1) pp += __shfl_xor(pp, d);
        if (tt == 0 && 2 * b + g < Btot) out[2 * b + g] = pp + bc2[0];
    }
#undef HNG
#undef NINR
}

// ======================= fallback: f32 kernel =======================
__device__ __forceinline__ void tile_fma_4x4(
    float acc[4][4], const float* in0, const float* in1, const float* in2,
    const float* in3, int k, const float* __restrict__ W, int wrow, int c4)
{
    float in_[4][4];
    *(float4*)&in_[0][0] = *(const float4*)(in0 + k);
    *(float4*)&in_[1][0] = *(const float4*)(in1 + k);
    *(float4*)&in_[2][0] = *(const float4*)(in2 + k);
    *(float4*)&in_[3][0] = *(const float4*)(in3 + k);
#pragma unroll
    for (int kk = 0; kk < 4; ++kk) {
        float w_[4];
        *(float4*)w_ = *(const float4*)&W[(wrow + kk) * 128 + c4];
#pragma unroll
        for (int r = 0; r < 4; ++r)
#pragma unroll
            for (int c = 0; c < 4; ++c)
                acc[r][c] += in_[r][kk] * w_[c];
    }
}

__global__ __launch_bounds__(256, 3) void gnn_fused(
    const float* __restrict__ gf, const float* __restrict__ nf,
    const float* __restrict__ ef, const void* __restrict__ nmask_raw,
    const float* __restrict__ Wn, const float* __restrict__ bn,
    const float* __restrict__ We, const float* __restrict__ be,
    const float* __restrict__ Ws, const float* __restrict__ bs,
    const float* __restrict__ Wg, const float* __restrict__ bg,
    const float* __restrict__ Wc1, const float* __restrict__ bc1,
    const float* __restrict__ Wc2, const float* __restrict__ bc2,
    float* __restrict__ out)
{
    const int b = blockIdx.x;
    const int t = threadIdx.x;

    __shared__ __align__(16) float s_g[GD_];
    __shared__ int   s_mi[N_];
    __shared__ float s_emask[N_];
    __shared__ __align__(16) float s_ef[N_][ED_];
    __shared__ __align__(16) float s_efm[N_][ED_];
    __shared__ __align__(16) float s_nin[N_][32];
    __shared__ __align__(16) float s_hn[N_ + 1][HN_];
    __shared__ __align__(16) float s_he[N_][HE_];
    __shared__ __align__(16) float s_bias1[HN_];
    __shared__ __align__(16) float s_bias2[HE_];
    __shared__ float s_sc[N_];
    __shared__ float s_w[N_];
    __shared__ __align__(16) float s_tmp[256];
    __shared__ __align__(16) float s_aggf[HE_];
    __shared__ __align__(16) float s_hg[HG_];
    __shared__ __align__(16) float s_hc[HC_];

    const unsigned char* mb = (const unsigned char*)nmask_raw;
    int cnt = __syncthreads_count(mb[t] != 0);
    const bool is_u8 = (cnt > 96);

    if (t < GD_) s_g[t] = gf[b * GD_ + t];
    for (int idx = t; idx < N_ * ND_; idx += 256)
        s_nin[idx >> 4][idx & 15] = nf[b * N_ * ND_ + idx];
    for (int idx = t; idx < (N_ - 1) * ED_; idx += 256)
        s_ef[idx >> 3][idx & 7] = ef[b * (N_ - 1) * ED_ + idx];
    if (t < ED_) s_ef[N_ - 1][t] = 0.0f;
    if (t < HN_) s_hn[N_][t] = 0.0f;
    if (t < N_) {
        int mv = is_u8 ? (int)mb[b * N_ + t] : ((const int*)nmask_raw)[b * N_ + t];
        s_mi[t] = mv;
    }
    __syncthreads();

    if (t < N_)
        s_emask[t] = (t < N_ - 1 && s_mi[t] != 0 && s_mi[t + 1] != 0) ? 1.0f : 0.0f;
    __syncthreads();

    {
        int e = t >> 3, k = t & 7;
        s_efm[e][k] = s_ef[e][k] * s_emask[e];
    }
    {
        int j = t & 127;
        if (t < 128) {
            float v = bn[j];
#pragma unroll
            for (int k = 0; k < GD_; ++k)
                v += s_g[k] * Wn[(ND_ + 2 * ED_ + k) * HN_ + j];
            s_bias1[j] = v;
        } else {
            float v = be[j];
#pragma unroll
            for (int k = 0; k < GD_; ++k)
                v += s_g[k] * We[(ED_ + 2 * HN_ + k) * HE_ + j];
            s_bias2[j] = v;
        }
    }
    __syncthreads();

    for (int idx = t; idx < N_ * 16; idx += 256) {
        int n = idx >> 4, kk = idx & 15;
        if (kk < 8) s_nin[n][16 + kk]       = (n > 0)      ? s_efm[n - 1][kk] : 0.0f;
        else        s_nin[n][24 + (kk - 8)] = (n < N_ - 1) ? s_efm[n][kk - 8] : 0.0f;
    }
    __syncthreads();

    const int jg = t & 31, rg = t >> 5;
    const int c4 = jg * 4, r4 = rg * 4;

    {
        float acc[4][4];
#pragma unroll
        for (int r = 0; r < 4; ++r)
#pragma unroll
            for (int c = 0; c < 4; ++c) acc[r][c] = s_bias1[c4 + c];
        const float* i0 = &s_nin[r4 + 0][0];
        const float* i1 = &s_nin[r4 + 1][0];
        const float* i2 = &s_nin[r4 + 2][0];
        const float* i3 = &s_nin[r4 + 3][0];
#pragma unroll
        for (int k = 0; k < 32; k += 4)
            tile_fma_4x4(acc, i0, i1, i2, i3, k, Wn, k, c4);
#pragma unroll
        for (int r = 0; r < 4; ++r)
#pragma unroll
            for (int c = 0; c < 4; ++c)
                s_hn[r4 + r][c4 + c] = fmaxf(acc[r][c], 0.0f);
    }
    __syncthreads();

    {
        float acc[4][4];
#pragma unroll
        for (int r = 0; r < 4; ++r)
#pragma unroll
            for (int c = 0; c < 4; ++c) acc[r][c] = s_bias2[c4 + c];
        {
            const float* i0 = &s_ef[r4 + 0][0];
            const float* i1 = &s_ef[r4 + 1][0];
            const float* i2 = &s_ef[r4 + 2][0];
            const float* i3 = &s_ef[r4 + 3][0];
#pragma unroll
            for (int k = 0; k < 8; k += 4)
                tile_fma_4x4(acc, i0, i1, i2, i3, k, We, k, c4);
        }
        {
            const float* i0 = &s_hn[r4 + 0][0];
            const float* i1 = &s_hn[r4 + 1][0];
            const float* i2 = &s_hn[r4 + 2][0];
            const float* i3 = &s_hn[r4 + 3][0];
#pragma unroll 4
            for (int k = 0; k < 128; k += 4)
                tile_fma_4x4(acc, i0, i1, i2, i3, k, We, 8 + k, c4);
        }
        {
            const float* i0 = &s_hn[r4 + 1][0];
            const float* i1 = &s_hn[r4 + 2][0];
            const float* i2 = &s_hn[r4 + 3][0];
            const float* i3 = &s_hn[r4 + 4][0];
#pragma unroll 4
            for (int k = 0; k < 128; k += 4)
                tile_fma_4x4(acc, i0, i1, i2, i3, k, We, 136 + k, c4);
        }
#pragma unroll
        for (int r = 0; r < 4; ++r)
#pragma unroll
            for (int c = 0; c < 4; ++c)
                s_he[r4 + r][c4 + c] = fmaxf(acc[r][c], 0.0f);
    }
    __syncthreads();

    {
        int c = t & 7, e = t >> 3;
        const float* he = &s_he[e][0];
        float p = 0.0f;
#pragma unroll
        for (int j0 = 0; j0 < 16; j0 += 4) {
            float4 h = *(const float4*)&he[c * 16 + j0];
            float4 wv = *(const float4*)&Ws[c * 16 + j0];
            p += h.x * wv.x + h.y * wv.y + h.z * wv.z + h.w * wv.w;
        }
        p += __shfl_xor(p, 1);
        p += __shfl_xor(p, 2);
        p += __shfl_xor(p, 4);
        if (c == 0) s_sc[e] = p + bs[0];
    }
    __syncthreads();
    if (t < 64) {
        float v = -INFINITY;
        if (t < N_ - 1)
            v = s_sc[t] * s_emask[t] + (1.0f - s_emask[t]) * (-1e9f);
        float m = v;
#pragma unroll
        for (int d = 32; d >= 1; d >>= 1) m = fmaxf(m, __shfl_xor(m, d));
        float e_ = (t < N_ - 1) ? expf(v - m) : 0.0f;
        float ssum = e_;
#pragma unroll
        for (int d = 32; d >= 1; d >>= 1) ssum += __shfl_xor(ssum, d);
        if (t < N_) s_w[t] = (t < N_ - 1) ? (e_ / ssum) : 0.0f;
    }
    __syncthreads();

    {
        int j = t & 127, half = t >> 7;
        float p = 0.0f;
#pragma unroll
        for (int e = 0; e < 16; ++e) {
            int ee = half * 16 + e;
            p += s_he[ee][j] * s_w[ee];
        }
        s_tmp[half * 128 + j] = p;
    }
    __syncthreads();
    if (t < 128) s_aggf[t] = s_tmp[t] + s_tmp[128 + t];
    __syncthreads();

    {
        int j = t & 127, half = t >> 7;
        float p = 0.0f;
        for (int k = half * 64; k < half * 64 + 64; ++k)
            p += s_aggf[k] * Wg[k * HG_ + j];
        s_tmp[half * 128 + j] = p;
    }
    __syncthreads();
    if (t < 128) s_hg[t] = fmaxf(s_tmp[t] + s_tmp[128 + t] + bg[t], 0.0f);
    __syncthreads();

    {
        int j = t & 63, q = t >> 6;
        float p = 0.0f;
        for (int k = q * 32; k < q * 32 + 32; ++k)
            p += s_hg[k] * Wc1[k * HC_ + j];
        s_tmp[q * 64 + j] = p;
    }
    __syncthreads();
    if (t < 64)
        s_hc[t] = fmaxf(s_tmp[t] + s_tmp[64 + t] + s_tmp[128 + t] + s_tmp[192 + t] + bc1[t], 0.0f);
    __syncthreads();

    if (t < 64) {
        float p = s_hc[t] * Wc2[t];
#pragma unroll
        for (int d = 32; d >= 1; d >>= 1) p += __shfl_xor(p, d);
        if (t == 0) out[b] = p + bc2[0];
    }
}

extern "C" void kernel_launch(void* const* d_in, const int* in_sizes, int n_in,
                              void* d_out, int out_size, void* d_ws, size_t ws_size,
                              hipStream_t stream) {
    const float* gf  = (const float*)d_in[0];
    const float* nf  = (const float*)d_in[1];
    const float* ef  = (const float*)d_in[2];
    const void*  nm  = d_in[3];
    const float* Wn  = (const float*)d_in[4];
    const float* bn  = (const float*)d_in[5];
    const float* We  = (const float*)d_in[6];
    const float* be  = (const float*)d_in[7];
    const float* Ws  = (const float*)d_in[8];
    const float* bs  = (const float*)d_in[9];
    const float* Wg  = (const float*)d_in[10];
    const float* bg  = (const float*)d_in[11];
    const float* Wc1 = (const float*)d_in[12];
    const float* bc1 = (const float*)d_in[13];
    const float* Wc2 = (const float*)d_in[14];
    const float* bc2 = (const float*)d_in[15];
    float* out = (float*)d_out;

    const int B = in_sizes[0] / GD_;

    if (ws_size >= (size_t)WS_BYTES && B >= 2) {
        prep_weights<<<20, 256, 0, stream>>>(Wn, We, (unsigned short*)d_ws);
        const int NB = (B + 1) / 2;
        gnn_mfma11<<<NB, 256, 0, stream>>>(gf, nf, ef, nm, Wn, bn, We, be, Ws, bs,
                                           Wg, bg, Wc1, bc1, Wc2, bc2,
                                           (const unsigned short*)d_ws, out, B);
    } else {
        gnn_fused<<<B, 256, 0, stream>>>(gf, nf, ef, nm, Wn, bn, We, be, Ws, bs,
                                         Wg, bg, Wc1, bc1, Wc2, bc2, out);
    }
}

// Round 18
// 77.353 us; speedup vs baseline: 1.0252x; 1.0252x over previous
//
#include <hip/hip_runtime.h>
#include <hip/hip_bf16.h>

#define N_  32
#define ND_ 16
#define ED_ 8
#define GD_ 8
#define HN_ 128
#define HE_ 128
#define HG_ 128
#define HC_ 64

typedef __attribute__((ext_vector_type(8))) short short8_t;
typedef __attribute__((ext_vector_type(4))) short short4_t;
typedef __attribute__((ext_vector_type(4))) float f32x4;

#define MFMA16(a, b, c) __builtin_amdgcn_mfma_f32_16x16x32_bf16((a), (b), (c), 0, 0, 0)

__device__ __forceinline__ unsigned short f2bf(float f) {
    unsigned int u = __float_as_uint(f);
    unsigned int r = u + 0x7FFFu + ((u >> 16) & 1u);
    return (unsigned short)(r >> 16);
}
__device__ __forceinline__ float bf2f(unsigned short h) {
    return __uint_as_float(((unsigned int)h) << 16);
}

// ---- workspace layout (ushort elements) ----
#define WNS_HI 0
#define WNS_LO 4096
#define WES_HI 8192
#define WES_LO (8192 + 36864)
#define WS_USHORTS (8192 + 2 * 36864)
#define WS_BYTES (WS_USHORTS * 2)

// Prologue: convert + swizzle weights into B-fragment-major bf16 hi/lo.
// lane l holds B[k = 32*s + 8*(l>>4)+i][col = 16*n + (l&15)]
// Edge sets 0..4 = W1' (We rows 8..135 then 0..7 then zero-pad to K=160);
// sets 5..8 = W2 (We rows 136..263).
__global__ void prep_weights(const float* __restrict__ Wn,
                             const float* __restrict__ We,
                             unsigned short* __restrict__ wsp) {
    int gid = blockIdx.x * 256 + threadIdx.x;
    if (gid >= 512 + 4608) return;
    float vals[8];
    unsigned short* dh;
    unsigned short* dl;
    if (gid < 512) {
        int l = gid & 63, n = (gid >> 6) & 7;
        int c = 16 * n + (l & 15);
#pragma unroll
        for (int i = 0; i < 8; ++i) {
            int k = 8 * (l >> 4) + i;
            vals[i] = Wn[k * HN_ + c];
        }
        dh = wsp + WNS_HI + gid * 8;
        dl = wsp + WNS_LO + gid * 8;
    } else {
        int g2 = gid - 512;
        int l = g2 & 63, n = (g2 >> 6) & 7, s = g2 >> 9;   // s in 0..8
        int c = 16 * n + (l & 15);
#pragma unroll
        for (int i = 0; i < 8; ++i) {
            int kl = 8 * (l >> 4) + i;
            int ks;
            if (s <= 4) {                      // W1': hn(128) | ef(8) | 0(24)
                int kf = s * 32 + kl;          // 0..159
                ks = (kf < 128) ? (8 + kf) : ((kf < 136) ? (kf - 128) : -1);
            } else {                           // W2: h_node[e+1]
                ks = 136 + (s - 5) * 32 + kl;
            }
            vals[i] = (ks >= 0) ? We[ks * HE_ + c] : 0.0f;
        }
        dh = wsp + WES_HI + g2 * 8;
        dl = wsp + WES_LO + g2 * 8;
    }
    unsigned short h[8], lo[8];
#pragma unroll
    for (int i = 0; i < 8; ++i) {
        h[i] = f2bf(vals[i]);
        lo[i] = f2bf(vals[i] - bf2f(h[i]));
    }
    *(short8_t*)dh = *(short8_t*)h;
    *(short8_t*)dl = *(short8_t*)lo;
}

#define HNS 168   // hn' row stride (ushorts): 336B = 84 dwords (== 20 mod 32, benign)
#define NIS 40    // nin row stride (ushorts): 80B = 20 dwords (== 20 mod 32, benign)
#define HES 128   // he f32 row stride (plain; swizzle removed — was net-neutral/negative)

// Load 4 edge B-fragments of set ss (0..4 = W1' steps, 5..8 = W2 steps).
// [0],[1] = hi (n-tiles 2w, 2w+1); [2],[3] = lo.
#define LOADB(Bv, ss) do {                                                      \
    Bv[0] = *(const short8_t*)(wsp + WES_HI + ((ss)*8 + 2*w)     * 512 + l*8);  \
    Bv[1] = *(const short8_t*)(wsp + WES_HI + ((ss)*8 + 2*w + 1) * 512 + l*8);  \
    Bv[2] = *(const short8_t*)(wsp + WES_LO + ((ss)*8 + 2*w)     * 512 + l*8);  \
    Bv[3] = *(const short8_t*)(wsp + WES_LO + ((ss)*8 + 2*w + 1) * 512 + l*8);  \
} while (0)

// 2 graphs / 256-thread block, ~40KB LDS -> 4 blocks/CU.
// Weights fetched once per PAIR. hn + nin single bf16.
__global__ __launch_bounds__(256, 4) void gnn_mfma12(
    const float* __restrict__ gf, const float* __restrict__ nf,
    const float* __restrict__ ef, const void* __restrict__ nmask_raw,
    const float* __restrict__ Wn, const float* __restrict__ bn,
    const float* __restrict__ We, const float* __restrict__ be,
    const float* __restrict__ Ws, const float* __restrict__ bs,
    const float* __restrict__ Wg, const float* __restrict__ bg,
    const float* __restrict__ Wc1, const float* __restrict__ bc1,
    const float* __restrict__ Wc2, const float* __restrict__ bc2,
    const unsigned short* __restrict__ wsp,
    float* __restrict__ out, int Btot)
{
    const int b = blockIdx.x;
    const int t = threadIdx.x;
    const int gid0 = 2 * b;
    const int gid1 = (2 * b + 1 < Btot) ? (2 * b + 1) : (Btot - 1);

    // UNI: { hn(g0)[33][168] @0 | hn(g1) @11088 | nin[64][40] @22176 (27296B) }
    //      -> overlaid by he f32 [64][128] (32768B) after edge barrier
    __shared__ __align__(16) unsigned char UNI[32768];
    // U3: { efrF f32[64][8] @0 (A->C) -> tmpF[512] @0 | aggf[2][128] @2048 | hg[2][128] @3072 }
    __shared__ __align__(16) unsigned char U3[4096];
    __shared__ __align__(16) float s_bias1[2][HN_];
    __shared__ __align__(16) float s_bias2[2][HE_];
    __shared__ float s_g[2][GD_];
    __shared__ int   s_mi[2][N_];
    __shared__ float s_emask[2][N_];
    __shared__ float s_sc[2][N_];
    __shared__ float s_w[2][N_];

#define HNG(g, row) ((unsigned short*)(UNI + (g) * 11088) + (row) * HNS)
    unsigned short* ninH = (unsigned short*)(UNI + 22176);   // [64][40]
#define NINR(r) (ninH + (r) * NIS)
    float* heF  = (float*)UNI;                               // [64][128]
    float* efrF = (float*)U3;                                // [64][8]
    float* tmpF = (float*)U3;                                // [512] (P5+)
    float* aggf = (float*)(U3 + 2048);                       // [2][128]
    float* hgF  = (float*)(U3 + 3072);                       // [2][128]

    // ---- mask dtype detection (u8 vs i32), deterministic ----
    const unsigned char* mb = (const unsigned char*)nmask_raw;
    int cnt = __syncthreads_count(mb[t] != 0);
    const bool is_u8 = (cnt > 96);

    // ---- Phase A: loads + zero fills ----
    if (t < 16) s_g[t >> 3][t & 7] = gf[(t >> 3 ? gid1 : gid0) * GD_ + (t & 7)];
    {   // node feats 2x32x16 -> single bf16, float4-vectorized (1 load/thread)
        int idx4 = t * 4;
        int gg = idx4 >> 9, rem = idx4 & 511;
        float4 v = *(const float4*)(nf + (gg ? gid1 : gid0) * 512 + rem);
        unsigned short hv[4] = {f2bf(v.x), f2bf(v.y), f2bf(v.z), f2bf(v.w)};
        *(short4_t*)&NINR(gg * 32 + (rem >> 4))[rem & 15] = *(short4_t*)hv;
    }
#pragma unroll
    for (int ii = 0; ii < 2; ++ii) {                 // raw edges f32 (row31=0)
        int idx = t + ii * 256;
        int gg = idx >> 8, rem = idx & 255, e = rem >> 3, k = rem & 7;
        efrF[(gg * 32 + e) * 8 + k] =
            (e < 31) ? ef[(gg ? gid1 : gid0) * 248 + e * 8 + k] : 0.0f;
    }
    if (t < 16) {                                     // node0 backward zero (both graphs)
        int gg = t >> 3, k = t & 7;
        NINR(gg * 32)[16 + k] = 0;
    }
    for (int idx = t; idx < 2 * HNS; idx += 256) {    // hn pad row 32 = 0 (both)
        int g = idx >= HNS, c = idx - g * HNS;
        HNG(g, N_)[c] = 0;
    }
    for (int idx = t; idx < 2 * 32 * 24; idx += 256) {  // hn cols 136..159 = 0 (both)
        int g = idx >= 768, r2 = idx - g * 768;
        int rr = r2 / 24, cc = 136 + (r2 % 24);
        HNG(g, rr)[cc] = 0;
    }
    if (t < 64) {
        int g = t >> 5, n = t & 31;
        int mv = is_u8 ? (int)mb[(g ? gid1 : gid0) * N_ + n]
                       : ((const int*)nmask_raw)[(g ? gid1 : gid0) * N_ + n];
        s_mi[g][n] = mv;
    }
    __syncthreads();

    // ---- Phase B: edge mask + combined biases (dual-graph per weight load) ----
    if (t < 64) {
        int g = t >> 5, n = t & 31;
        s_emask[g][n] = (n < 31 && s_mi[g][n] != 0 && s_mi[g][n + 1] != 0) ? 1.0f : 0.0f;
    }
    {
        int mat = t >> 7, j = t & 127;
        const float* Wt = mat ? (We + (ED_ + 2 * HN_) * HE_) : (Wn + (ND_ + 2 * ED_) * HN_);
        float base = mat ? be[j] : bn[j];
        float a0 = base, a1 = base;
#pragma unroll
        for (int k = 0; k < GD_; ++k) {
            float wv = Wt[k * 128 + j];
            a0 += s_g[0][k] * wv;
            a1 += s_g[1][k] * wv;
        }
        if (mat) { s_bias2[0][j] = a0; s_bias2[1][j] = a1; }
        else     { s_bias1[0][j] = a0; s_bias1[1][j] = a1; }
    }
    __syncthreads();

    // ---- Phase C: raw-ef -> hn cols 128..135 (single bf16); masked -> nin tail ----
#pragma unroll
    for (int ii = 0; ii < 2; ++ii) {
        int idx = t + ii * 256;
        int gg = idx >> 8, rem = idx & 255, e = rem >> 3, k = rem & 7;
        int r = gg * 32 + e;
        float vr = efrF[r * 8 + k];                       // raw (row31 = 0)
        HNG(gg, e)[128 + k] = f2bf(vr);
        bool m = (e < 31) && s_mi[gg][e] != 0 && s_mi[gg][e + 1] != 0;
        unsigned short hm = f2bf(m ? vr : 0.0f);
        if (e < 31) NINR(r + 1)[16 + k] = hm;
        NINR(r)[24 + k] = hm;
    }
    __syncthreads();

    const int w = t >> 6, l = t & 63;
    const int lrow = l & 15;
    const int lk8 = (l >> 4) * 8;
    const int g4 = (l >> 4) * 4;
    const int c0 = 32 * w + lrow, c1 = c0 + 16;

    // ---- Node MLP (MFMA, K=32, single-bf16 A, split B): 4 M-tiles (2/graph) ----
    {
        const unsigned short* pn = wsp + (2 * w) * 512 + l * 8;
        short8_t nBh0 = *(const short8_t*)(pn + WNS_HI);
        short8_t nBl0 = *(const short8_t*)(pn + WNS_LO);
        short8_t nBh1 = *(const short8_t*)(pn + WNS_HI + 512);
        short8_t nBl1 = *(const short8_t*)(pn + WNS_LO + 512);

        f32x4 acc[4][2];
#pragma unroll
        for (int mt = 0; mt < 4; ++mt) {
            int g = mt >> 1;
            float b0 = s_bias1[g][c0], b1 = s_bias1[g][c1];
            acc[mt][0] = (f32x4){b0, b0, b0, b0};
            acc[mt][1] = (f32x4){b1, b1, b1, b1};
        }
#pragma unroll
        for (int mt = 0; mt < 4; ++mt) {
            int r = (mt >> 1) * 32 + (mt & 1) * 16 + lrow;
            short8_t A = *(const short8_t*)&NINR(r)[lk8];
            acc[mt][0] = MFMA16(A, nBl0, acc[mt][0]);
            acc[mt][0] = MFMA16(A, nBh0, acc[mt][0]);
            acc[mt][1] = MFMA16(A, nBl1, acc[mt][1]);
            acc[mt][1] = MFMA16(A, nBh1, acc[mt][1]);
        }
#pragma unroll
        for (int mt = 0; mt < 4; ++mt) {
            int g = mt >> 1, rb = (mt & 1) * 16 + g4;
#pragma unroll
            for (int nt = 0; nt < 2; ++nt) {
                int col = nt ? c1 : c0;
#pragma unroll
                for (int r = 0; r < 4; ++r)
                    HNG(g, rb + r)[col] = f2bf(fmaxf(acc[mt][nt][r], 0.0f));
            }
        }
    }
    __syncthreads();

    // ---- Edge MLP (all-MFMA): acc = bias2 + hn'[e]@W1' + hn[e+1]@W2 ----
    {
        f32x4 acc[4][2];
#pragma unroll
        for (int mt = 0; mt < 4; ++mt) {
            int g = mt >> 1;
            float b0 = s_bias2[g][c0], b1 = s_bias2[g][c1];
            acc[mt][0] = (f32x4){b0, b0, b0, b0};
            acc[mt][1] = (f32x4){b1, b1, b1, b1};
        }
        short8_t B1[4], B2[4];
        LOADB(B1, 0);
#pragma unroll
        for (int s = 0; s < 4; ++s) {
            LOADB(B2, 5 + s);
            int kb = s * 32 + lk8;
#pragma unroll
            for (int mt = 0; mt < 4; ++mt) {
                int g = mt >> 1, lr = (mt & 1) * 16 + lrow;
                short8_t A1 = *(const short8_t*)&HNG(g, lr)[kb];
                acc[mt][0] = MFMA16(A1, B1[2], acc[mt][0]);
                acc[mt][0] = MFMA16(A1, B1[0], acc[mt][0]);
                acc[mt][1] = MFMA16(A1, B1[3], acc[mt][1]);
                acc[mt][1] = MFMA16(A1, B1[1], acc[mt][1]);
            }
            LOADB(B1, s + 1);    // W1' sets 1..4
#pragma unroll
            for (int mt = 0; mt < 4; ++mt) {
                int g = mt >> 1, lr = (mt & 1) * 16 + lrow;
                short8_t A2 = *(const short8_t*)&HNG(g, lr + 1)[kb];
                acc[mt][0] = MFMA16(A2, B2[2], acc[mt][0]);
                acc[mt][0] = MFMA16(A2, B2[0], acc[mt][0]);
                acc[mt][1] = MFMA16(A2, B2[3], acc[mt][1]);
                acc[mt][1] = MFMA16(A2, B2[1], acc[mt][1]);
            }
        }
        {   // final W1' step 4: ef columns (kb = 128..159)
            int kb = 128 + lk8;
#pragma unroll
            for (int mt = 0; mt < 4; ++mt) {
                int g = mt >> 1, lr = (mt & 1) * 16 + lrow;
                short8_t A1 = *(const short8_t*)&HNG(g, lr)[kb];
                acc[mt][0] = MFMA16(A1, B1[2], acc[mt][0]);
                acc[mt][0] = MFMA16(A1, B1[0], acc[mt][0]);
                acc[mt][1] = MFMA16(A1, B1[3], acc[mt][1]);
                acc[mt][1] = MFMA16(A1, B1[1], acc[mt][1]);
            }
        }
        __syncthreads();   // all hn/nin reads done -> safe to overlay he onto UNI
#pragma unroll
        for (int mt = 0; mt < 4; ++mt) {
            int g = mt >> 1, rb = (mt & 1) * 16 + g4;
#pragma unroll
            for (int nt = 0; nt < 2; ++nt) {
                int col = nt ? c1 : c0;
#pragma unroll
                for (int r = 0; r < 4; ++r)
                    heF[(g * 32 + rb + r) * HES + col] = fmaxf(acc[mt][nt][r], 0.0f);
            }
        }
    }
    __syncthreads();

    // ---- P3: scores (64 edges x 4 lanes x 32 cols) ----
    {
        int c = t & 3, eg = t >> 2;
        int g = eg >> 5, e = eg & 31;
        const float* he = &heF[(g * 32 + e) * HES];
        float pq = 0.0f;
#pragma unroll
        for (int j0 = 0; j0 < 32; j0 += 4) {
            float4 h = *(const float4*)&he[c * 32 + j0];
            float4 wv = *(const float4*)&Ws[c * 32 + j0];
            pq += h.x * wv.x + h.y * wv.y + h.z * wv.z + h.w * wv.w;
        }
        pq += __shfl_xor(pq, 1);
        pq += __shfl_xor(pq, 2);
        if (c == 0) s_sc[g][e] = pq + bs[0];
    }
    __syncthreads();

    // ---- masked softmax (graph g on wave g) ----
    if (t < 128) {
        int g = t >> 6, tt = t & 63;
        float v = -INFINITY;
        if (tt < 31)
            v = s_sc[g][tt] * s_emask[g][tt] + (1.0f - s_emask[g][tt]) * (-1e9f);
        float m = v;
#pragma unroll
        for (int d = 32; d >= 1; d >>= 1) m = fmaxf(m, __shfl_xor(m, d));
        float e_ = (tt < 31) ? expf(v - m) : 0.0f;
        float ssum = e_;
#pragma unroll
        for (int d = 32; d >= 1; d >>= 1) ssum += __shfl_xor(ssum, d);
        if (tt < 32) s_w[g][tt] = (tt < 31) ? (e_ / ssum) : 0.0f;
    }
    __syncthreads();

    // ---- P4: weighted edge pooling ----
    {
        int g = t >> 7, j = t & 127;
        float pp = 0.0f;
#pragma unroll
        for (int e = 0; e < 31; ++e)
            pp += heF[(g * 32 + e) * HES + j] * s_w[g][e];
        aggf[g * 128 + j] = pp;
    }
    __syncthreads();

    // ---- P5: h_glob (Wg loaded once per pair; tmpF overlays dead efrF) ----
    {
        int j = t & 127, half = t >> 7;
        float a0 = 0.0f, a1 = 0.0f;
        for (int k = half * 64; k < half * 64 + 64; ++k) {
            float wv = Wg[k * HG_ + j];
            a0 += aggf[k] * wv;
            a1 += aggf[128 + k] * wv;
        }
        tmpF[half * 256 + j] = a0;
        tmpF[half * 256 + 128 + j] = a1;
    }
    __syncthreads();
    {
        int g = t >> 7, j = t & 127;
        hgF[g * 128 + j] = fmaxf(tmpF[g * 128 + j] + tmpF[256 + g * 128 + j] + bg[j], 0.0f);
    }
    __syncthreads();

    // ---- P6: h_cls (Wc1 loaded once per pair), P7 fused ----
    {
        int j = t & 63, q = t >> 6;
        float a0 = 0.0f, a1 = 0.0f;
        for (int k = q * 32; k < q * 32 + 32; ++k) {
            float wv = Wc1[k * HC_ + j];
            a0 += hgF[k] * wv;
            a1 += hgF[128 + k] * wv;
        }
        tmpF[q * 128 + j] = a0;
        tmpF[q * 128 + 64 + j] = a1;
    }
    __syncthreads();
    if (t < 128) {
        int g = t >> 6, tt = t & 63;
        float hc = bc1[tt];
#pragma unroll
        for (int q = 0; q < 4; ++q) hc += tmpF[q * 128 + g * 64 + tt];
        hc = fmaxf(hc, 0.0f);
        float pp = hc * Wc2[tt];
#pragma unroll
        for (int d = 32; d >= 1; d >>= 1) pp += __shfl_xor(pp, d);
        if (tt == 0 && 2 * b + g < Btot) out[2 * b + g] = pp + bc2[0];
    }
#undef HNG
#undef NINR
}

// ======================= fallback: f32 kernel =======================
__device__ __forceinline__ void tile_fma_4x4(
    float acc[4][4], const float* in0, const float* in1, const float* in2,
    const float* in3, int k, const float* __restrict__ W, int wrow, int c4)
{
    float in_[4][4];
    *(float4*)&in_[0][0] = *(const float4*)(in0 + k);
    *(float4*)&in_[1][0] = *(const float4*)(in1 + k);
    *(float4*)&in_[2][0] = *(const float4*)(in2 + k);
    *(float4*)&in_[3][0] = *(const float4*)(in3 + k);
#pragma unroll
    for (int kk = 0; kk < 4; ++kk) {
        float w_[4];
        *(float4*)w_ = *(const float4*)&W[(wrow + kk) * 128 + c4];
#pragma unroll
        for (int r = 0; r < 4; ++r)
#pragma unroll
            for (int c = 0; c < 4; ++c)
                acc[r][c] += in_[r][kk] * w_[c];
    }
}

__global__ __launch_bounds__(256, 3) void gnn_fused(
    const float* __restrict__ gf, const float* __restrict__ nf,
    const float* __restrict__ ef, const void* __restrict__ nmask_raw,
    const float* __restrict__ Wn, const float* __restrict__ bn,
    const float* __restrict__ We, const float* __restrict__ be,
    const float* __restrict__ Ws, const float* __restrict__ bs,
    const float* __restrict__ Wg, const float* __restrict__ bg,
    const float* __restrict__ Wc1, const float* __restrict__ bc1,
    const float* __restrict__ Wc2, const float* __restrict__ bc2,
    float* __restrict__ out)
{
    const int b = blockIdx.x;
    const int t = threadIdx.x;

    __shared__ __align__(16) float s_g[GD_];
    __shared__ int   s_mi[N_];
    __shared__ float s_emask[N_];
    __shared__ __align__(16) float s_ef[N_][ED_];
    __shared__ __align__(16) float s_efm[N_][ED_];
    __shared__ __align__(16) float s_nin[N_][32];
    __shared__ __align__(16) float s_hn[N_ + 1][HN_];
    __shared__ __align__(16) float s_he[N_][HE_];
    __shared__ __align__(16) float s_bias1[HN_];
    __shared__ __align__(16) float s_bias2[HE_];
    __shared__ float s_sc[N_];
    __shared__ float s_w[N_];
    __shared__ __align__(16) float s_tmp[256];
    __shared__ __align__(16) float s_aggf[HE_];
    __shared__ __align__(16) float s_hg[HG_];
    __shared__ __align__(16) float s_hc[HC_];

    const unsigned char* mb = (const unsigned char*)nmask_raw;
    int cnt = __syncthreads_count(mb[t] != 0);
    const bool is_u8 = (cnt > 96);

    if (t < GD_) s_g[t] = gf[b * GD_ + t];
    for (int idx = t; idx < N_ * ND_; idx += 256)
        s_nin[idx >> 4][idx & 15] = nf[b * N_ * ND_ + idx];
    for (int idx = t; idx < (N_ - 1) * ED_; idx += 256)
        s_ef[idx >> 3][idx & 7] = ef[b * (N_ - 1) * ED_ + idx];
    if (t < ED_) s_ef[N_ - 1][t] = 0.0f;
    if (t < HN_) s_hn[N_][t] = 0.0f;
    if (t < N_) {
        int mv = is_u8 ? (int)mb[b * N_ + t] : ((const int*)nmask_raw)[b * N_ + t];
        s_mi[t] = mv;
    }
    __syncthreads();

    if (t < N_)
        s_emask[t] = (t < N_ - 1 && s_mi[t] != 0 && s_mi[t + 1] != 0) ? 1.0f : 0.0f;
    __syncthreads();

    {
        int e = t >> 3, k = t & 7;
        s_efm[e][k] = s_ef[e][k] * s_emask[e];
    }
    {
        int j = t & 127;
        if (t < 128) {
            float v = bn[j];
#pragma unroll
            for (int k = 0; k < GD_; ++k)
                v += s_g[k] * Wn[(ND_ + 2 * ED_ + k) * HN_ + j];
            s_bias1[j] = v;
        } else {
            float v = be[j];
#pragma unroll
            for (int k = 0; k < GD_; ++k)
                v += s_g[k] * We[(ED_ + 2 * HN_ + k) * HE_ + j];
            s_bias2[j] = v;
        }
    }
    __syncthreads();

    for (int idx = t; idx < N_ * 16; idx += 256) {
        int n = idx >> 4, kk = idx & 15;
        if (kk < 8) s_nin[n][16 + kk]       = (n > 0)      ? s_efm[n - 1][kk] : 0.0f;
        else        s_nin[n][24 + (kk - 8)] = (n < N_ - 1) ? s_efm[n][kk - 8] : 0.0f;
    }
    __syncthreads();

    const int jg = t & 31, rg = t >> 5;
    const int c4 = jg * 4, r4 = rg * 4;

    {
        float acc[4][4];
#pragma unroll
        for (int r = 0; r < 4; ++r)
#pragma unroll
            for (int c = 0; c < 4; ++c) acc[r][c] = s_bias1[c4 + c];
        const float* i0 = &s_nin[r4 + 0][0];
        const float* i1 = &s_nin[r4 + 1][0];
        const float* i2 = &s_nin[r4 + 2][0];
        const float* i3 = &s_nin[r4 + 3][0];
#pragma unroll
        for (int k = 0; k < 32; k += 4)
            tile_fma_4x4(acc, i0, i1, i2, i3, k, Wn, k, c4);
#pragma unroll
        for (int r = 0; r < 4; ++r)
#pragma unroll
            for (int c = 0; c < 4; ++c)
                s_hn[r4 + r][c4 + c] = fmaxf(acc[r][c], 0.0f);
    }
    __syncthreads();

    {
        float acc[4][4];
#pragma unroll
        for (int r = 0; r < 4; ++r)
#pragma unroll
            for (int c = 0; c < 4; ++c) acc[r][c] = s_bias2[c4 + c];
        {
            const float* i0 = &s_ef[r4 + 0][0];
            const float* i1 = &s_ef[r4 + 1][0];
            const float* i2 = &s_ef[r4 + 2][0];
            const float* i3 = &s_ef[r4 + 3][0];
#pragma unroll
            for (int k = 0; k < 8; k += 4)
                tile_fma_4x4(acc, i0, i1, i2, i3, k, We, k, c4);
        }
        {
            const float* i0 = &s_hn[r4 + 0][0];
            const float* i1 = &s_hn[r4 + 1][0];
            const float* i2 = &s_hn[r4 + 2][0];
            const float* i3 = &s_hn[r4 + 3][0];
#pragma unroll 4
            for (int k = 0; k < 128; k += 4)
                tile_fma_4x4(acc, i0, i1, i2, i3, k, We, 8 + k, c4);
        }
        {
            const float* i0 = &s_hn[r4 + 1][0];
            const float* i1 = &s_hn[r4 + 2][0];
            const float* i2 = &s_hn[r4 + 3][0];
            const float* i3 = &s_hn[r4 + 4][0];
#pragma unroll 4
            for (int k = 0; k < 128; k += 4)
                tile_fma_4x4(acc, i0, i1, i2, i3, k, We, 136 + k, c4);
        }
#pragma unroll
        for (int r = 0; r < 4; ++r)
#pragma unroll
            for (int c = 0; c < 4; ++c)
                s_he[r4 + r][c4 + c] = fmaxf(acc[r][c], 0.0f);
    }
    __syncthreads();

    {
        int c = t & 7, e = t >> 3;
        const float* he = &s_he[e][0];
        float p = 0.0f;
#pragma unroll
        for (int j0 = 0; j0 < 16; j0 += 4) {
            float4 h = *(const float4*)&he[c * 16 + j0];
            float4 wv = *(const float4*)&Ws[c * 16 + j0];
            p += h.x * wv.x + h.y * wv.y + h.z * wv.z + h.w * wv.w;
        }
        p += __shfl_xor(p, 1);
        p += __shfl_xor(p, 2);
        p += __shfl_xor(p, 4);
        if (c == 0) s_sc[e] = p + bs[0];
    }
    __syncthreads();
    if (t < 64) {
        float v = -INFINITY;
        if (t < N_ - 1)
            v = s_sc[t] * s_emask[t] + (1.0f - s_emask[t]) * (-1e9f);
        float m = v;
#pragma unroll
        for (int d = 32; d >= 1; d >>= 1) m = fmaxf(m, __shfl_xor(m, d));
        float e_ = (t < N_ - 1) ? expf(v - m) : 0.0f;
        float ssum = e_;
#pragma unroll
        for (int d = 32; d >= 1; d >>= 1) ssum += __shfl_xor(ssum, d);
        if (t < N_) s_w[t] = (t < N_ - 1) ? (e_ / ssum) : 0.0f;
    }
    __syncthreads();

    {
        int j = t & 127, half = t >> 7;
        float p = 0.0f;
#pragma unroll
        for (int e = 0; e < 16; ++e) {
            int ee = half * 16 + e;
            p += s_he[ee][j] * s_w[ee];
        }
        s_tmp[half * 128 + j] = p;
    }
    __syncthreads();
    if (t < 128) s_aggf[t] = s_tmp[t] + s_tmp[128 + t];
    __syncthreads();

    {
        int j = t & 127, half = t >> 7;
        float p = 0.0f;
        for (int k = half * 64; k < half * 64 + 64; ++k)
            p += s_aggf[k] * Wg[k * HG_ + j];
        s_tmp[half * 128 + j] = p;
    }
    __syncthreads();
    if (t < 128) s_hg[t] = fmaxf(s_tmp[t] + s_tmp[128 + t] + bg[t], 0.0f);
    __syncthreads();

    {
        int j = t & 63, q = t >> 6;
        float p = 0.0f;
        for (int k = q * 32; k < q * 32 + 32; ++k)
            p += s_hg[k] * Wc1[k * HC_ + j];
        s_tmp[q * 64 + j] = p;
    }
    __syncthreads();
    if (t < 64)
        s_hc[t] = fmaxf(s_tmp[t] + s_tmp[64 + t] + s_tmp[128 + t] + s_tmp[192 + t] + bc1[t], 0.0f);
    __syncthreads();

    if (t < 64) {
        float p = s_hc[t] * Wc2[t];
#pragma unroll
        for (int d = 32; d >= 1; d >>= 1) p += __shfl_xor(p, d);
        if (t == 0) out[b] = p + bc2[0];
    }
}

extern "C" void kernel_launch(void* const* d_in, const int* in_sizes, int n_in,
                              void* d_out, int out_size, void* d_ws, size_t ws_size,
                              hipStream_t stream) {
    const float* gf  = (const float*)d_in[0];
    const float* nf  = (const float*)d_in[1];
    const float* ef  = (const float*)d_in[2];
    const void*  nm  = d_in[3];
    const float* Wn  = (const float*)d_in[4];
    const float* bn  = (const float*)d_in[5];
    const float* We  = (const float*)d_in[6];
    const float* be  = (const float*)d_in[7];
    const float* Ws  = (const float*)d_in[8];
    const float* bs  = (const float*)d_in[9];
    const float* Wg  = (const float*)d_in[10];
    const float* bg  = (const float*)d_in[11];
    const float* Wc1 = (const float*)d_in[12];
    const float* bc1 = (const float*)d_in[13];
    const float* Wc2 = (const float*)d_in[14];
    const float* bc2 = (const float*)d_in[15];
    float* out = (float*)d_out;

    const int B = in_sizes[0] / GD_;

    if (ws_size >= (size_t)WS_BYTES && B >= 2) {
        prep_weights<<<20, 256, 0, stream>>>(Wn, We, (unsigned short*)d_ws);
        const int NB = (B + 1) / 2;
        gnn_mfma12<<<NB, 256, 0, stream>>>(gf, nf, ef, nm, Wn, bn, We, be, Ws, bs,
                                           Wg, bg, Wc1, bc1, Wc2, bc2,
                                           (const unsigned short*)d_ws, out, B);
    } else {
        gnn_fused<<<B, 256, 0, stream>>>(gf, nf, ef, nm, Wn, bn, We, be, Ws, bs,
                                         Wg, bg, Wc1, bc1, Wc2, bc2, out);
    }
}